// Round 1
// baseline (381.302 us; speedup 1.0000x reference)
//
#include <hip/hip_runtime.h>
#include <math.h>

// Problem constants
#define TT 2048        // b*n tokens
#define DD 1024        // model dim
#define HH 8           // heads
#define NKK 256        // keys per half
#define KDD 128        // key dim
#define TK 8           // top-k
#define NEE 65536      // experts

// ws layout (bytes)
#define WS_PS    0           // double[32][1024] partial sums
#define WS_PQ    262144      // double[32][1024] partial sumsq
#define WS_A     524288      // float[1024] scale
#define WS_B2    528384      // float[1024] shift
#define WS_XN    1048576     // float[2048][1024]
#define WS_Q     9437184     // float[2048][2048]
#define WS_SIM   26214400    // float[2][2048][8][256]
#define WS_IDX   59768832    // int[2048][8][8]
#define WS_SMW   60293120    // float[2048][8][8]
// total ~60.8 MB

// ---------------- BatchNorm statistics ----------------
__global__ __launch_bounds__(256) void bn_partial(const float* __restrict__ x,
    double* __restrict__ ps, double* __restrict__ pq)
{
    int col = blockIdx.x * 256 + threadIdx.x;
    int r0 = blockIdx.y * 64;
    double s = 0.0, q = 0.0;
    for (int r = 0; r < 64; ++r) {
        double v = (double)x[(size_t)(r0 + r) * DD + col];
        s += v; q += v * v;
    }
    ps[(size_t)blockIdx.y * DD + col] = s;
    pq[(size_t)blockIdx.y * DD + col] = q;
}

__global__ __launch_bounds__(256) void bn_final(const double* __restrict__ ps,
    const double* __restrict__ pq, const float* __restrict__ gamma,
    const float* __restrict__ beta, float* __restrict__ Aout, float* __restrict__ Bout)
{
    int col = blockIdx.x * 256 + threadIdx.x;
    double s = 0.0, q = 0.0;
    for (int g = 0; g < 32; ++g) { s += ps[(size_t)g * DD + col]; q += pq[(size_t)g * DD + col]; }
    double mu = s / 2048.0;
    double var = q / 2048.0 - mu * mu;      // biased var, matches torch/jax BN
    double rstd = 1.0 / sqrt(var + 1e-5);
    Aout[col] = (float)((double)gamma[col] * rstd);
    Bout[col] = (float)((double)beta[col] - mu * (double)gamma[col] * rstd);
}

__global__ __launch_bounds__(256) void xn_kernel(const float* __restrict__ x,
    const float* __restrict__ A, const float* __restrict__ B2, float* __restrict__ XN)
{
    int i = blockIdx.x * 256 + threadIdx.x;   // float4 index
    float4 v = ((const float4*)x)[i];
    int c = (i & 255) << 2;
    v.x = v.x * A[c + 0] + B2[c + 0];
    v.y = v.y * A[c + 1] + B2[c + 1];
    v.z = v.z * A[c + 2] + B2[c + 2];
    v.w = v.w * A[c + 3] + B2[c + 3];
    ((float4*)XN)[i] = v;
}

// ---------------- fp32 tile GEMM: C[m][n] = sum_k A[m][k]*B[n][k] ----------------
// mode 0: Q = XN @ w_q.T          (M=2048, N=2048, K=1024)
// mode 1: per-(p,h) sim GEMM via blockIdx.z  (M=2048, N=256, K=128)
__global__ __launch_bounds__(256) void gemm_nt(
    const float* __restrict__ Abase, const float* __restrict__ Bbase,
    float* __restrict__ Cbase, int lda, int ldb, int ldc, int Kdim, int mode)
{
    const float* A = Abase; const float* B = Bbase; float* C = Cbase;
    if (mode == 1) {
        int z = blockIdx.z;                 // z = p*8+h
        int p = z >> 3, h = z & 7;
        A += (size_t)z * 128;               // column offset into Q
        B += (size_t)h * (NKK * 2 * KDD) + (size_t)p * KDD;
        C += (size_t)p * ((size_t)TT * HH * NKK) + (size_t)h * NKK;
    }
    __shared__ float As[16][132];
    __shared__ float Bs[16][132];
    int tid = threadIdx.x;
    int tx = tid & 15, ty = tid >> 4;
    int m0 = blockIdx.x * 128, n0 = blockIdx.y * 128;
    float acc[8][8];
#pragma unroll
    for (int i = 0; i < 8; ++i)
#pragma unroll
        for (int j = 0; j < 8; ++j) acc[i][j] = 0.f;

    for (int k0 = 0; k0 < Kdim; k0 += 16) {
#pragma unroll
        for (int it = 0; it < 2; ++it) {
            int li = tid + it * 256;        // 0..511
            int row = li >> 2;              // 0..127
            int kc = (li & 3) << 2;         // 0,4,8,12
            float4 va = *(const float4*)(A + (size_t)(m0 + row) * lda + k0 + kc);
            As[kc + 0][row] = va.x; As[kc + 1][row] = va.y;
            As[kc + 2][row] = va.z; As[kc + 3][row] = va.w;
            float4 vb = *(const float4*)(B + (size_t)(n0 + row) * ldb + k0 + kc);
            Bs[kc + 0][row] = vb.x; Bs[kc + 1][row] = vb.y;
            Bs[kc + 2][row] = vb.z; Bs[kc + 3][row] = vb.w;
        }
        __syncthreads();
#pragma unroll
        for (int k = 0; k < 16; ++k) {
            float a[8], b[8];
            *(float4*)&a[0] = *(const float4*)&As[k][ty * 4];
            *(float4*)&a[4] = *(const float4*)&As[k][64 + ty * 4];
            *(float4*)&b[0] = *(const float4*)&Bs[k][tx * 4];
            *(float4*)&b[4] = *(const float4*)&Bs[k][64 + tx * 4];
#pragma unroll
            for (int i = 0; i < 8; ++i)
#pragma unroll
                for (int j = 0; j < 8; ++j) acc[i][j] += a[i] * b[j];
        }
        __syncthreads();
    }
#pragma unroll
    for (int i = 0; i < 8; ++i) {
        int m = m0 + ((i < 4) ? (ty * 4 + i) : (64 + ty * 4 + (i - 4)));
        float4 c0 = make_float4(acc[i][0], acc[i][1], acc[i][2], acc[i][3]);
        float4 c1 = make_float4(acc[i][4], acc[i][5], acc[i][6], acc[i][7]);
        *(float4*)(C + (size_t)m * ldc + n0 + tx * 4) = c0;
        *(float4*)(C + (size_t)m * ldc + n0 + 64 + tx * 4) = c1;
    }
}

// ---------------- two-stage top-k + softmax (one wave per (t,h)) ----------------
__global__ __launch_bounds__(256) void topk_kernel(
    const float* __restrict__ SIM, int* __restrict__ IDX, float* __restrict__ SMW)
{
    int gw = blockIdx.x * 4 + (threadIdx.x >> 6);   // 0..16383
    int lane = threadIdx.x & 63;
    int t = gw >> 3, h = gw & 7;

    float vx = 0.f, vy = 0.f; int vix = 0, viy = 0;

    // stage 1, p = 0 : lane (lane>>3) keeps the (lane>>3)-th ranked (val,idx)
    {
        const float* s = SIM + ((size_t)t * HH + h) * NKK;
        float v0 = s[lane], v1 = s[lane + 64], v2 = s[lane + 128], v3 = s[lane + 192];
#pragma unroll
        for (int it = 0; it < 8; ++it) {
            float bv = v0; int bj = 0;
            if (v1 > bv) { bv = v1; bj = 1; }
            if (v2 > bv) { bv = v2; bj = 2; }
            if (v3 > bv) { bv = v3; bj = 3; }
            int mi = lane + (bj << 6);
            float mv = bv;
#pragma unroll
            for (int off = 1; off < 64; off <<= 1) {
                float ov = __shfl_xor(mv, off);
                int oi = __shfl_xor(mi, off);
                if (ov > mv || (ov == mv && oi < mi)) { mv = ov; mi = oi; }
            }
            if ((lane >> 3) == it) { vx = mv; vix = mi; }
            if (mi == lane)            v0 = -INFINITY;
            else if (mi == lane + 64)  v1 = -INFINITY;
            else if (mi == lane + 128) v2 = -INFINITY;
            else if (mi == lane + 192) v3 = -INFINITY;
        }
    }
    // stage 1, p = 1 : lane (lane&7) keeps the (lane&7)-th ranked (val,idx)
    {
        const float* s = SIM + (size_t)TT * HH * NKK + ((size_t)t * HH + h) * NKK;
        float v0 = s[lane], v1 = s[lane + 64], v2 = s[lane + 128], v3 = s[lane + 192];
#pragma unroll
        for (int it = 0; it < 8; ++it) {
            float bv = v0; int bj = 0;
            if (v1 > bv) { bv = v1; bj = 1; }
            if (v2 > bv) { bv = v2; bj = 2; }
            if (v3 > bv) { bv = v3; bj = 3; }
            int mi = lane + (bj << 6);
            float mv = bv;
#pragma unroll
            for (int off = 1; off < 64; off <<= 1) {
                float ov = __shfl_xor(mv, off);
                int oi = __shfl_xor(mi, off);
                if (ov > mv || (ov == mv && oi < mi)) { mv = ov; mi = oi; }
            }
            if ((lane & 7) == it) { vy = mv; viy = mi; }
            if (mi == lane)            v0 = -INFINITY;
            else if (mi == lane + 64)  v1 = -INFINITY;
            else if (mi == lane + 128) v2 = -INFINITY;
            else if (mi == lane + 192) v3 = -INFINITY;
        }
    }

    // stage 2: lane = cx*8+cy holds combo score; extract top-8 of 64
    float mycs = vx + vy;                 // combo score (flat index = lane)
    int cidx = vix * NKK + viy;           // expert index
    float s2[8]; int wi2[8];
#pragma unroll
    for (int it = 0; it < 8; ++it) {
        float mv = mycs; int ml = lane;
#pragma unroll
        for (int off = 1; off < 64; off <<= 1) {
            float ov = __shfl_xor(mv, off);
            int ol = __shfl_xor(ml, off);
            if (ov > mv || (ov == mv && ol < ml)) { mv = ov; ml = ol; }
        }
        s2[it] = mv;
        wi2[it] = __shfl(cidx, ml);
        if (lane == ml) mycs = -INFINITY;
    }
    // softmax over the 8 scores (s2[0] is the max)
    float e[8]; float esum = 0.f;
#pragma unroll
    for (int it = 0; it < 8; ++it) { e[it] = expf(s2[it] - s2[0]); esum += e[it]; }
    float inv = 1.f / esum;
    if (lane == 0) {
        int base = (t * HH + h) * TK;
#pragma unroll
        for (int it = 0; it < 8; ++it) { IDX[base + it] = wi2[it]; SMW[base + it] = e[it] * inv; }
    }
}

// ---------------- expert gather + gelu + weighted combine ----------------
__global__ __launch_bounds__(256) void expert_kernel(
    const float* __restrict__ x, const int* __restrict__ IDX,
    const float* __restrict__ SMW, const float* __restrict__ key_in,
    const float* __restrict__ key_out, float* __restrict__ out)
{
    int t = blockIdx.x;
    int tid = threadIdx.x, lane = tid & 63, w = tid >> 6;
    __shared__ float xs[DD];
    __shared__ float part[4][DD];
    *(float4*)&xs[tid * 4] = *(const float4*)(x + (size_t)t * DD + tid * 4);
    __syncthreads();
    float4 xin[4];
#pragma unroll
    for (int r = 0; r < 4; ++r) xin[r] = *(const float4*)&xs[r * 256 + lane * 4];
    float4 acc[4];
#pragma unroll
    for (int r = 0; r < 4; ++r) acc[r] = make_float4(0.f, 0.f, 0.f, 0.f);

    for (int hh2 = 0; hh2 < 2; ++hh2) {
        int hh = w * 2 + hh2;
        for (int k = 0; k < TK; ++k) {
            int base = (t * HH + hh) * TK + k;
            int e = IDX[base];
            float wt = SMW[base];
            const float* ki = key_in + (size_t)e * DD;
            const float* ko = key_out + (size_t)e * DD;
            float4 kin[4], kout[4];
#pragma unroll
            for (int r = 0; r < 4; ++r) kin[r] = *(const float4*)(ki + r * 256 + lane * 4);
#pragma unroll
            for (int r = 0; r < 4; ++r) kout[r] = *(const float4*)(ko + r * 256 + lane * 4);
            float p = 0.f;
#pragma unroll
            for (int r = 0; r < 4; ++r)
                p += xin[r].x * kin[r].x + xin[r].y * kin[r].y
                   + xin[r].z * kin[r].z + xin[r].w * kin[r].w;
#pragma unroll
            for (int off = 1; off < 64; off <<= 1) p += __shfl_xor(p, off);
            float g = 0.5f * p * (1.f + erff(p * 0.70710678118654752440f));
            float go = g * wt;
#pragma unroll
            for (int r = 0; r < 4; ++r) {
                acc[r].x += go * kout[r].x; acc[r].y += go * kout[r].y;
                acc[r].z += go * kout[r].z; acc[r].w += go * kout[r].w;
            }
        }
    }
#pragma unroll
    for (int r = 0; r < 4; ++r) *(float4*)&part[w][r * 256 + lane * 4] = acc[r];
    __syncthreads();
    int c = tid * 4;
    float4 s0 = *(const float4*)&part[0][c];
    float4 s1 = *(const float4*)&part[1][c];
    float4 s2 = *(const float4*)&part[2][c];
    float4 s3 = *(const float4*)&part[3][c];
    float4 o;
    o.x = (s0.x + s1.x) + (s2.x + s3.x);
    o.y = (s0.y + s1.y) + (s2.y + s3.y);
    o.z = (s0.z + s1.z) + (s2.z + s3.z);
    o.w = (s0.w + s1.w) + (s2.w + s3.w);
    *(float4*)(out + (size_t)t * DD + c) = o;
}

extern "C" void kernel_launch(void* const* d_in, const int* in_sizes, int n_in,
                              void* d_out, int out_size, void* d_ws, size_t ws_size,
                              hipStream_t stream)
{
    const float* x       = (const float*)d_in[0];
    const float* gamma   = (const float*)d_in[1];
    const float* beta    = (const float*)d_in[2];
    const float* w_q     = (const float*)d_in[3];
    const float* keys    = (const float*)d_in[4];
    const float* key_in  = (const float*)d_in[5];
    const float* key_out = (const float*)d_in[6];
    float* out = (float*)d_out;
    char* ws = (char*)d_ws;

    double* ps  = (double*)(ws + WS_PS);
    double* pq  = (double*)(ws + WS_PQ);
    float*  Aw  = (float*)(ws + WS_A);
    float*  B2w = (float*)(ws + WS_B2);
    float*  XN  = (float*)(ws + WS_XN);
    float*  Q   = (float*)(ws + WS_Q);
    float*  SIMw= (float*)(ws + WS_SIM);
    int*    IDXw= (int*)(ws + WS_IDX);
    float*  SMWw= (float*)(ws + WS_SMW);

    bn_partial<<<dim3(4, 32), 256, 0, stream>>>(x, ps, pq);
    bn_final<<<4, 256, 0, stream>>>(ps, pq, gamma, beta, Aw, B2w);
    xn_kernel<<<2048, 256, 0, stream>>>(x, Aw, B2w, XN);
    // Q = XN @ w_q.T : M=2048 N=2048 K=1024
    gemm_nt<<<dim3(16, 16, 1), 256, 0, stream>>>(XN, w_q, Q, 1024, 1024, 2048, 1024, 0);
    // sim[p][t][h][key] : per (p,h) GEMM, M=2048 N=256 K=128
    gemm_nt<<<dim3(16, 2, 16), 256, 0, stream>>>(Q, keys, SIMw, 2048, 256, 2048, 128, 1);
    topk_kernel<<<4096, 256, 0, stream>>>(SIMw, IDXw, SMWw);
    expert_kernel<<<2048, 256, 0, stream>>>(x, IDXw, SMWw, key_in, key_out, out);
}